// Round 8
// baseline (1182.817 us; speedup 1.0000x reference)
//
#include <hip/hip_runtime.h>
#include <math.h>

// CRITICAL: no FMA contraction — bit-replicating numpy's SSE float32 einsum.
#pragma clang fp contract(off)

#define T_TOKENS 16384
#define HDIM 2048
#define NEXP 64
#define TOPK 6
#define SEQ 4096
#define TPB 32          // tokens per block
#define NTHR 256        // 4 waves
#define KC 64           // k-chunk staged in LDS
#define WS 68           // padded LDS stride for W tile (proven ~free, round 3)
#define LGS 65          // padded stride for logits/probs scratch

// numpy einsum contig_two micro-step (SSE, 4 lanes, no FMA), proven bit-exact:
// per 16-k block, SSE lane l chains k = 4j + l, applied j = 3..0:
//   v = a0*b0 + (a1*b1 + (a2*b2 + (a3*b3 + v)))
__device__ __forceinline__ void np_upd(const float4& w0, const float4& w1,
                                       const float4& w2, const float4& w3,
                                       const float4& x0, const float4& x1,
                                       const float4& x2, const float4& x3,
                                       float acc[4])
{
    acc[0] = w0.x*x0.x + (w1.x*x1.x + (w2.x*x2.x + (w3.x*x3.x + acc[0])));
    acc[1] = w0.y*x0.y + (w1.y*x1.y + (w2.y*x2.y + (w3.y*x3.y + acc[1])));
    acc[2] = w0.z*x0.z + (w1.z*x1.z + (w2.z*x2.z + (w3.z*x3.z + acc[2])));
    acc[3] = w0.w*x0.w + (w1.w*x1.w + (w2.w*x2.w + (w3.w*x3.w + acc[3])));
}

// Thread layout (256 thr): le = tid&15 -> experts {le, le+16, le+32, le+48}
//   grp = tid>>4 (0..15) -> tokens grp*2, grp*2+1
// W: staged global->LDS per 64-k chunk, read as ds_read_b128 (round-3 pattern,
//    16-lane broadcast, ~free conflicts). x: DIRECT from global (float4, 16
//    lanes share each address -> 4 cache lines/instr), prefetched 1 b16 ahead.
// LDS pipe load drops 24 -> 16 b128/wave-b16 vs round 3.
__global__ __launch_bounds__(NTHR, 2) void moe_gate_main(
    const float* __restrict__ x, const float* __restrict__ wgt,
    float* __restrict__ out, float* __restrict__ gacc)
{
    __shared__ float w_lds[NEXP * WS];    // 17408 B
    __shared__ float lg[TPB * LGS];       //  8320 B
    __shared__ float probs[TPB * LGS];    //  8320 B
    __shared__ float psum[4 * NEXP];      //  1024 B
    __shared__ int   cnt[NEXP];           //   256 B

    const int tid = threadIdx.x;
    const int bid = blockIdx.x;
    const int tb  = bid * TPB;
    const int b   = tb >> 12;             // /4096

    const int le    = tid & 15;
    const int grp   = tid >> 4;           // 0..15
    const int trow0 = grp * 2;

    const float* xp0 = x + (size_t)(tb + trow0) * HDIM;
    const float* xp1 = xp0 + HDIM;

    float acc[4][2][4];                   // [expert je][token tt][sse lane]
    #pragma unroll
    for (int je = 0; je < 4; ++je)
        #pragma unroll
        for (int tt = 0; tt < 2; ++tt)
            #pragma unroll
            for (int l = 0; l < 4; ++l) acc[je][tt][l] = 0.f;

    // x fragments for kb=0 (2 tokens x 4 float4)
    float4 xc[2][4], xn[2][4];
    #pragma unroll
    for (int j = 0; j < 4; ++j) {
        xc[0][j] = *reinterpret_cast<const float4*>(xp0 + 4 * j);
        xc[1][j] = *reinterpret_cast<const float4*>(xp1 + 4 * j);
    }

    for (int c = 0; c < HDIM / KC; ++c) {
        const int k0 = c * KC;
        __syncthreads();   // previous chunk's W readers done
        // ---- stage W chunk: 64 rows x 16 float4, 4 f4/thread (round-3 pattern)
        #pragma unroll
        for (int i = 0; i < 4; ++i) {
            int idx = i * NTHR + tid;
            int e = idx >> 4, c4 = idx & 15;
            float4 v = *reinterpret_cast<const float4*>(&wgt[e * HDIM + k0 + c4 * 4]);
            *reinterpret_cast<float4*>(&w_lds[e * WS + c4 * 4]) = v;
        }
        __syncthreads();

        #pragma unroll
        for (int b16 = 0; b16 < 4; ++b16) {
            const int kb = k0 + b16 * 16;
            // prefetch next b16's x into registers (crosses chunk boundary)
            if (kb + 16 < HDIM) {
                #pragma unroll
                for (int j = 0; j < 4; ++j) {
                    xn[0][j] = *reinterpret_cast<const float4*>(xp0 + kb + 16 + 4 * j);
                    xn[1][j] = *reinterpret_cast<const float4*>(xp1 + kb + 16 + 4 * j);
                }
            }
            const int lb = b16 * 16;
            #pragma unroll
            for (int je = 0; je < 4; ++je) {
                const float* wr = &w_lds[(le + 16 * je) * WS + lb];
                float4 w0 = *reinterpret_cast<const float4*>(wr);
                float4 w1 = *reinterpret_cast<const float4*>(wr + 4);
                float4 w2 = *reinterpret_cast<const float4*>(wr + 8);
                float4 w3 = *reinterpret_cast<const float4*>(wr + 12);
                np_upd(w0, w1, w2, w3, xc[0][0], xc[0][1], xc[0][2], xc[0][3], acc[je][0]);
                np_upd(w0, w1, w2, w3, xc[1][0], xc[1][1], xc[1][2], xc[1][3], acc[je][1]);
            }
            #pragma unroll
            for (int t = 0; t < 2; ++t)
                #pragma unroll
                for (int j = 0; j < 4; ++j) xc[t][j] = xn[t][j];
        }
    }

    // ---- logits: hadd exactly like npyv_sum_f32: (v0+v1)+(v2+v3)
    #pragma unroll
    for (int je = 0; je < 4; ++je)
        #pragma unroll
        for (int tt = 0; tt < 2; ++tt) {
            float v = (acc[je][tt][0] + acc[je][tt][1]) + (acc[je][tt][2] + acc[je][tt][3]);
            lg[(trow0 + tt) * LGS + le + 16 * je] = v;
        }
    if (tid < NEXP) cnt[tid] = 0;
    __syncthreads();

    // ---- softmax per token (threads 0..31), fp32, numpy pairwise sum
    if (tid < TPB) {
        const int t = tid;
        float mx = lg[t * LGS];
        for (int e = 1; e < NEXP; ++e) { float v = lg[t * LGS + e]; if (v > mx) mx = v; }
        for (int e = 0; e < NEXP; ++e)
            probs[t * LGS + e] = expf(lg[t * LGS + e] - mx);
        float r[8];
        #pragma unroll
        for (int j = 0; j < 8; ++j) r[j] = probs[t * LGS + j];
        for (int i = 8; i < 64; i += 8)
            #pragma unroll
            for (int j = 0; j < 8; ++j) r[j] += probs[t * LGS + i + j];
        float S = ((r[0] + r[1]) + (r[2] + r[3])) + ((r[4] + r[5]) + (r[6] + r[7]));
        for (int e = 0; e < NEXP; ++e) probs[t * LGS + e] = probs[t * LGS + e] / S;
    }
    __syncthreads();

    // ---- partial per-expert prob sums (aux loss), all 256 threads
    {
        const int e = tid & 63, q = tid >> 6;
        float s = 0.f;
        for (int t = q * 8; t < q * 8 + 8; ++t) s += probs[t * LGS + e];
        psum[q * 64 + e] = s;
    }
    __syncthreads();

    if (tid < TPB) {
        // ---- top-6 on probs, strict > ascending scan (tie -> lowest index)
        const int t = tid;
        const int gt = tb + t;
        float pv[TOPK]; int pi[TOPK];
        for (int r = 0; r < TOPK; ++r) {
            float bv = -1.f; int be = 0;
            for (int e = 0; e < NEXP; ++e) {
                float v = probs[t * LGS + e];
                if (v > bv) { bv = v; be = e; }
            }
            probs[t * LGS + be] = -1.f;
            pv[r] = bv; pi[r] = be;
            atomicAdd(&cnt[be], 1);
        }
        float wsum = pv[0];
        #pragma unroll
        for (int r = 1; r < TOPK; ++r) wsum += pv[r];
        wsum += 1e-20f;
        #pragma unroll
        for (int r = 0; r < TOPK; ++r) {
            out[(size_t)gt * TOPK + r] = (float)pi[r];
            out[(size_t)T_TOKENS * TOPK + (size_t)gt * TOPK + r] = pv[r] / wsum;
        }
    } else if (tid >= 64 && tid < 128) {
        const int e = tid - 64;
        float s = psum[e] + psum[64 + e] + psum[128 + e] + psum[192 + e];
        atomicAdd(&gacc[b * 64 + e], s);
    }
    __syncthreads();
    if (tid < NEXP) {
        atomicAdd(&gacc[256 + b * 64 + tid], (float)cnt[tid]);
    }
}

// Finalize: aux = ALPHA * mean_b( sum_e (cnt*E/(S*K)) * (ssum/S) )
__global__ __launch_bounds__(256) void moe_gate_aux(
    const float* __restrict__ gacc, float* __restrict__ out)
{
    __shared__ float red[4];
    const int tid = threadIdx.x;
    float v = gacc[256 + tid] * gacc[tid];
    #pragma unroll
    for (int o = 32; o > 0; o >>= 1) v += __shfl_down(v, o, 64);
    if ((tid & 63) == 0) red[tid >> 6] = v;
    __syncthreads();
    if (tid == 0) {
        float tot = red[0] + red[1] + red[2] + red[3];
        const float scale = (64.0f / (4096.0f * 6.0f)) / 4096.0f;
        out[2 * T_TOKENS * TOPK] = 1e-3f * (tot * scale) * 0.25f;
    }
}

extern "C" void kernel_launch(void* const* d_in, const int* in_sizes, int n_in,
                              void* d_out, int out_size, void* d_ws, size_t ws_size,
                              hipStream_t stream) {
    const float* x   = (const float*)d_in[0];
    const float* wgt = (const float*)d_in[1];
    float* out  = (float*)d_out;
    float* gacc = (float*)d_ws;

    hipMemsetAsync(d_ws, 0, 512 * sizeof(float), stream);
    moe_gate_main<<<T_TOKENS / TPB, NTHR, 0, stream>>>(x, wgt, out, gacc);
    moe_gate_aux<<<1, 256, 0, stream>>>(gacc, out);
}